// Round 21
// baseline (125.841 us; speedup 1.0000x reference)
//
#include <hip/hip_runtime.h>
#include <cstdint>
#include <cstddef>

#define NTOK 8192      // B*S
#define SLEN 2048
#define DM   768
#define NH   12
#define DKH  64

typedef __attribute__((ext_vector_type(8))) short bf16x8;
typedef __attribute__((ext_vector_type(4))) float f32x4;

__device__ __forceinline__ float b2f(unsigned short u) {
  return __uint_as_float(((unsigned)u) << 16);
}
__device__ __forceinline__ unsigned short f2b(float f) {
  unsigned u = __float_as_uint(f);
  u += 0x7fffu + ((u >> 16) & 1u);   // RNE (no NaN inputs here)
  return (unsigned short)(u >> 16);
}
__device__ __forceinline__ unsigned cvtpk(float lo, float hi) {
  unsigned r;
  asm("v_cvt_pk_bf16_f32 %0, %1, %2" : "=v"(r) : "v"(lo), "v"(hi));
  return r;
}

__device__ __forceinline__ void gld16(const void* g, void* l) {
  __builtin_amdgcn_global_load_lds(
      (const __attribute__((address_space(1))) void*)g,
      (__attribute__((address_space(3))) void*)l, 16, 0, 0);
}

#define BAR_DRAIN() do {                                  \
    asm volatile("s_waitcnt vmcnt(0)" ::: "memory");      \
    __builtin_amdgcn_s_barrier();                         \
    __builtin_amdgcn_sched_barrier(0);                    \
  } while (0)

// ---------------- fp32 -> bf16 cast: x + 4 weights in ONE launch -------------
__global__ void cast_all_kernel(const float* __restrict__ x,
                                const float* __restrict__ w0,
                                const float* __restrict__ w1,
                                const float* __restrict__ w2,
                                const float* __restrict__ w3,
                                unsigned short* __restrict__ xb,
                                unsigned short* __restrict__ wb) {
  const int bid = blockIdx.x, tid = threadIdx.x;
  const float* src;
  unsigned short* dst;
  size_t i;
  if (bid < 3072) {
    src = x; dst = xb; i = (size_t)bid * 256 + tid;
  } else {
    const int wbid = bid - 3072;
    const int w = wbid / 288;
    src = (w == 0) ? w0 : (w == 1) ? w1 : (w == 2) ? w2 : w3;
    dst = wb + (size_t)w * DM * DM;
    i = (size_t)(wbid - w * 288) * 256 + tid;
  }
  const float4* p = (const float4*)(src + i * 8);
  float4 a = p[0], b = p[1];
  union { unsigned short h[8]; bf16x8 v; } u;
  u.h[0] = f2b(a.x); u.h[1] = f2b(a.y); u.h[2] = f2b(a.z); u.h[3] = f2b(a.w);
  u.h[4] = f2b(b.x); u.h[5] = f2b(b.y); u.h[6] = f2b(b.z); u.h[7] = f2b(b.w);
  *(bf16x8*)(dst + i * 8) = u.v;
}

// ---------------- unified QKV GEMM: [8192 x 2304] = x @ [Wq;Wk;Wv]^T ---------
// NEW (r20): double-buffered LDS (48KB: 3 blocks/CU still fit — r9's loss was
// 64KB -> 2 blocks/CU) + single barrier per K-step, stage-ahead order (the r3
// attn lesson): stage(kk+1) -> compute(kk) -> drain. Halves barrier count and
// hides the stage's L2 latency under the MFMA phase.
__global__ __launch_bounds__(256, 3) void gemm_qkv_kernel(
    const unsigned short* __restrict__ A, const unsigned short* __restrict__ Ball,
    unsigned short* __restrict__ Qb, unsigned short* __restrict__ Kb,
    unsigned short* __restrict__ VTout,
    const int* __restrict__ pos) {
  const int K = DM;
  const int tid = threadIdx.x, wid = tid >> 6, lane = tid & 63;
  const int lrow = lane & 15, g = lane >> 4, lk8 = g * 8;
  const int m0 = blockIdx.y * 64, n0 = blockIdx.x * 128;
  const int wm = (wid >> 1) * 32, wn = (wid & 1) * 64;
  const int sr = wid * 8 + (lane >> 3), sc = (lane & 7) * 8;
  const int ssw = sc ^ ((sr & 7) << 3);
  __shared__ unsigned short At[2][64 * 64];    // 16KB
  __shared__ unsigned short Bt[2][128 * 64];   // 32KB
  f32x4 acc[2][4] = {};

  const unsigned short* ap = A    + (size_t)(m0 + sr) * K + ssw;
  const unsigned short* bp = Ball + (size_t)(n0 + sr) * K + ssw;

  int aoff[2][2], boff[2][4];
#pragma unroll
  for (int ks = 0; ks < 2; ++ks) {
#pragma unroll
    for (int mi = 0; mi < 2; ++mi) {
      int ra = wm + mi * 16 + lrow;
      aoff[ks][mi] = (ra * 64 + ((ks * 32 + lk8) ^ ((ra & 7) << 3))) * 2;
    }
#pragma unroll
    for (int ni = 0; ni < 4; ++ni) {
      int rb = wn + ni * 16 + lrow;
      boff[ks][ni] = (rb * 64 + ((ks * 32 + lk8) ^ ((rb & 7) << 3))) * 2;
    }
  }

  auto stage = [&](int buf) {
    gld16(ap,          &At[buf][(wid * 8) * 64]);
    gld16(ap + 32 * K, &At[buf][(32 + wid * 8) * 64]);
#pragma unroll
    for (int rnd = 0; rnd < 4; ++rnd)
      gld16(bp + rnd * 32 * K, &Bt[buf][(rnd * 32 + wid * 8) * 64]);
    ap += 64; bp += 64;
  };

  const int nk = K >> 6;
  stage(0);
  BAR_DRAIN();
  for (int kk = 0; kk < nk; ++kk) {
    const int cur = kk & 1;
    if (kk + 1 < nk) stage(cur ^ 1);
    const char* Atc = (const char*)&At[cur][0];
    const char* Btc = (const char*)&Bt[cur][0];
    bf16x8 af[2][2], bfr[2][4];
#pragma unroll
    for (int ks = 0; ks < 2; ++ks) {
#pragma unroll
      for (int mi = 0; mi < 2; ++mi)
        af[ks][mi] = *(const bf16x8*)(Atc + aoff[ks][mi]);
#pragma unroll
      for (int ni = 0; ni < 4; ++ni)
        bfr[ks][ni] = *(const bf16x8*)(Btc + boff[ks][ni]);
    }
#pragma unroll
    for (int ks = 0; ks < 2; ++ks)
#pragma unroll
      for (int mi = 0; mi < 2; ++mi)
#pragma unroll
        for (int ni = 0; ni < 4; ++ni)
          acc[mi][ni] = __builtin_amdgcn_mfma_f32_16x16x32_bf16(
              bfr[ks][ni], af[ks][mi], acc[mi][ni], 0, 0, 0);
    BAR_DRAIN();
  }

  const int nsec = blockIdx.x / 6;           // 0=Q, 1=K, 2=V
  const int nn0 = n0 - nsec * 768;

  if (nsec == 2) {                           // V -> transposed+permuted VT
#pragma unroll
    for (int mi = 0; mi < 2; ++mi) {
      const int m = m0 + wm + mi * 16 + lrow;
      const int bb = m >> 11, st = m & (SLEN - 1);
      const int scol = (st & ~63) | (st & 35) |
                       (((st >> 4) & 1) << 2) | (((st >> 2) & 1) << 3) |
                       (((st >> 3) & 1) << 4);
#pragma unroll
      for (int ni = 0; ni < 4; ++ni) {
        const int nb = nn0 + wn + ni * 16 + g * 4;
        const int hh = nb >> 6, dd = nb & 63;
        unsigned short* dst =
            VTout + ((size_t)(bb * NH + hh) * DKH + dd) * SLEN + scol;
#pragma unroll
        for (int r = 0; r < 4; ++r)
          dst[(size_t)r * SLEN] = f2b(acc[mi][ni][r]);
      }
    }
    return;
  }

  unsigned short* Cp = (nsec == 0) ? Qb : Kb;
  float frq[4][2];
#pragma unroll
  for (int ni = 0; ni < 4; ++ni)
#pragma unroll
    for (int rp = 0; rp < 2; ++rp)
      frq[ni][rp] = exp2f(
          (float)(((wn + ni * 16 + g * 4 + rp * 2) & 63) >> 1) *
          -0.4152410118609203f);
#pragma unroll
  for (int mi = 0; mi < 2; ++mi) {
    const int m = m0 + wm + mi * 16 + lrow;
    const float ps = (float)pos[m & (SLEN - 1)];
#pragma unroll
    for (int ni = 0; ni < 4; ++ni) {
#pragma unroll
      for (int rp = 0; rp < 2; ++rp) {
        float sn, cs;
        __sincosf(ps * frq[ni][rp], &sn, &cs);
        float x1 = acc[mi][ni][2 * rp], x2 = acc[mi][ni][2 * rp + 1];
        acc[mi][ni][2 * rp]     = fmaf(x1, cs, -x2 * sn);
        acc[mi][ni][2 * rp + 1] = fmaf(x1, sn, x2 * cs);
      }
      union { unsigned u[2]; ushort4 s; } o;
      o.u[0] = cvtpk(acc[mi][ni][0], acc[mi][ni][1]);
      o.u[1] = cvtpk(acc[mi][ni][2], acc[mi][ni][3]);
      *(ushort4*)&Cp[(size_t)m * DM + nn0 + wn + ni * 16 + g * 4] = o.s;
    }
  }
}

// ---------------- output projection GEMM (dbuf single-barrier, fp32 out) -----
__global__ __launch_bounds__(256, 3) void gemm_out_kernel(
    const unsigned short* __restrict__ A, const unsigned short* __restrict__ B,
    float* __restrict__ C) {
  const int K = DM, N = DM;
  const int tid = threadIdx.x, wid = tid >> 6, lane = tid & 63;
  const int lrow = lane & 15, g = lane >> 4, lk8 = g * 8;
  const int m0 = blockIdx.y * 64, n0 = blockIdx.x * 128;
  const int wm = (wid >> 1) * 32, wn = (wid & 1) * 64;
  const int sr = wid * 8 + (lane >> 3), sc = (lane & 7) * 8;
  const int ssw = sc ^ ((sr & 7) << 3);
  __shared__ unsigned short At[2][64 * 64];
  __shared__ unsigned short Bt[2][128 * 64];
  f32x4 acc[2][4] = {};

  const unsigned short* ap = A + (size_t)(m0 + sr) * K + ssw;
  const unsigned short* bp = B + (size_t)(n0 + sr) * K + ssw;

  int aoff[2][2], boff[2][4];
#pragma unroll
  for (int ks = 0; ks < 2; ++ks) {
#pragma unroll
    for (int mi = 0; mi < 2; ++mi) {
      int ra = wm + mi * 16 + lrow;
      aoff[ks][mi] = (ra * 64 + ((ks * 32 + lk8) ^ ((ra & 7) << 3))) * 2;
    }
#pragma unroll
    for (int ni = 0; ni < 4; ++ni) {
      int rb = wn + ni * 16 + lrow;
      boff[ks][ni] = (rb * 64 + ((ks * 32 + lk8) ^ ((rb & 7) << 3))) * 2;
    }
  }

  auto stage = [&](int buf) {
    gld16(ap,          &At[buf][(wid * 8) * 64]);
    gld16(ap + 32 * K, &At[buf][(32 + wid * 8) * 64]);
#pragma unroll
    for (int rnd = 0; rnd < 4; ++rnd)
      gld16(bp + rnd * 32 * K, &Bt[buf][(rnd * 32 + wid * 8) * 64]);
    ap += 64; bp += 64;
  };

  const int nk = K >> 6;
  stage(0);
  BAR_DRAIN();
  for (int kk = 0; kk < nk; ++kk) {
    const int cur = kk & 1;
    if (kk + 1 < nk) stage(cur ^ 1);
    const char* Atc = (const char*)&At[cur][0];
    const char* Btc = (const char*)&Bt[cur][0];
    bf16x8 af[2][2], bfr[2][4];
#pragma unroll
    for (int ks = 0; ks < 2; ++ks) {
#pragma unroll
      for (int mi = 0; mi < 2; ++mi)
        af[ks][mi] = *(const bf16x8*)(Atc + aoff[ks][mi]);
#pragma unroll
      for (int ni = 0; ni < 4; ++ni)
        bfr[ks][ni] = *(const bf16x8*)(Btc + boff[ks][ni]);
    }
#pragma unroll
    for (int ks = 0; ks < 2; ++ks)
#pragma unroll
      for (int mi = 0; mi < 2; ++mi)
#pragma unroll
        for (int ni = 0; ni < 4; ++ni)
          acc[mi][ni] = __builtin_amdgcn_mfma_f32_16x16x32_bf16(
              bfr[ks][ni], af[ks][mi], acc[mi][ni], 0, 0, 0);
    BAR_DRAIN();
  }

#pragma unroll
  for (int mi = 0; mi < 2; ++mi) {
    const int m = m0 + wm + mi * 16 + lrow;
#pragma unroll
    for (int ni = 0; ni < 4; ++ni)
      *(f32x4*)&C[(size_t)m * N + n0 + wn + ni * 16 + g * 4] = acc[mi][ni];
  }
}

// ---------------- causal flash attention: QBLK=64, best-measured config ------
// (r20 = r17-best, byte-identical; falsified levers listed in r19 notes.)
__global__ __launch_bounds__(256, 4) void attn_kernel(
    const unsigned short* __restrict__ Q, const unsigned short* __restrict__ Kg,
    const unsigned short* __restrict__ VT, unsigned short* __restrict__ O) {
  const int bh = blockIdx.x;                 // %8 pins XCD
  const int s = 31 - (int)blockIdx.y;        // 64-row q-subtile, heavy first
  const int nt = s + 1;                      // kv tiles needed
  const int b = bh / NH, h = bh - b * NH;
  const size_t base = ((size_t)b * SLEN) * DM + h * DKH;
  const size_t vbase = (size_t)bh * DKH * SLEN;
  const int tid = threadIdx.x, wid = tid >> 6, lane = tid & 63;
  const int lrow = lane & 15, g = lane >> 4;
  const int rloc = wid * 16 + lrow;          // row within the 64-row subtile

  __shared__ unsigned short Kt[2][64 * 64];  // 16KB
  __shared__ unsigned short Vt[2][64 * 64];  // 16KB

  bf16x8 qf[2];
#pragma unroll
  for (int ks = 0; ks < 2; ++ks) {
    union { unsigned short h[8]; bf16x8 v; } u;
    u.v = *(const bf16x8*)&Q[base + (size_t)(s * 64 + rloc) * DM + ks * 32 + g * 8];
#pragma unroll
    for (int j = 0; j < 8; ++j)
      u.h[j] = f2b(b2f(u.h[j]) * 0.18033688011112042f);
    qf[ks] = u.v;
  }

  union { unsigned short h[8]; bf16x8 v; } one_u;
#pragma unroll
  for (int j = 0; j < 8; ++j) one_u.h[j] = 0x3F80;
  const bf16x8 ones = one_u.v;

  f32x4 oacc[4] = {};
  f32x4 l_acc = {};

  const int srow = wid * 8 + (lane >> 3);
  const int ssw = ((lane & 7) * 8) ^ ((srow & 7) << 3);
  const unsigned short* kp = Kg + base + (size_t)srow * DM + ssw;
  const unsigned short* vp = VT + vbase + (size_t)srow * SLEN + ssw;

  int roff[2][4];
#pragma unroll
  for (int ks = 0; ks < 2; ++ks)
#pragma unroll
    for (int ni = 0; ni < 4; ++ni) {
      int rr = ni * 16 + lrow;
      roff[ks][ni] = (rr * 64 + ((ks * 32 + g * 8) ^ ((rr & 7) << 3))) * 2;
    }

  auto stage = [&](int buf) {
    gld16(kp,             &Kt[buf][(wid * 8) * 64]);
    gld16(kp + 32 * DM,   &Kt[buf][(32 + wid * 8) * 64]);
    gld16(vp,             &Vt[buf][(wid * 8) * 64]);
    gld16(vp + 32 * SLEN, &Vt[buf][(32 + wid * 8) * 64]);
    kp += 64 * DM;
    vp += 64;
  };

  auto compute = [&](int t, int buf) {
    const char* Ksb = (const char*)&Kt[buf][0];
    const char* Vsb = (const char*)&Vt[buf][0];

    f32x4 sa[4] = {};
    __builtin_amdgcn_s_setprio(1);
#pragma unroll
    for (int ks = 0; ks < 2; ++ks)
#pragma unroll
      for (int ni = 0; ni < 4; ++ni) {
        bf16x8 kf = *(const bf16x8*)(Ksb + roff[ks][ni]);
        sa[ni] = __builtin_amdgcn_mfma_f32_16x16x32_bf16(
            kf, qf[ks], sa[ni], 0, 0, 0);
      }
    __builtin_amdgcn_s_setprio(0);

    if (t == s) {                            // diagonal tile: causal mask
#pragma unroll
      for (int ni = 0; ni < 4; ++ni)
#pragma unroll
        for (int r = 0; r < 4; ++r)
          if (ni * 16 + g * 4 + r > rloc) sa[ni][r] = -1e30f;
    }

#pragma unroll
    for (int ni = 0; ni < 4; ++ni)
#pragma unroll
      for (int r = 0; r < 4; ++r)
        sa[ni][r] = exp2f(sa[ni][r]);

    bf16x8 pf[2];
#pragma unroll
    for (int ks = 0; ks < 2; ++ks) {
      union { unsigned u[4]; bf16x8 v; } uu;
      uu.u[0] = cvtpk(sa[2 * ks][0],     sa[2 * ks][1]);
      uu.u[1] = cvtpk(sa[2 * ks][2],     sa[2 * ks][3]);
      uu.u[2] = cvtpk(sa[2 * ks + 1][0], sa[2 * ks + 1][1]);
      uu.u[3] = cvtpk(sa[2 * ks + 1][2], sa[2 * ks + 1][3]);
      pf[ks] = uu.v;
    }

    __builtin_amdgcn_s_setprio(1);
#pragma unroll
    for (int ks = 0; ks < 2; ++ks) {
#pragma unroll
      for (int ni = 0; ni < 4; ++ni) {
        bf16x8 vf = *(const bf16x8*)(Vsb + roff[ks][ni]);
        oacc[ni] = __builtin_amdgcn_mfma_f32_16x16x32_bf16(
            vf, pf[ks], oacc[ni], 0, 0, 0);
      }
      l_acc = __builtin_amdgcn_mfma_f32_16x16x32_bf16(
          ones, pf[ks], l_acc, 0, 0, 0);
    }
    __builtin_amdgcn_s_setprio(0);
  };

  stage(0);
  BAR_DRAIN();
  int cur = 0;
  for (int t = 0; t < nt; ++t) {
    if (t + 1 < nt) stage(cur ^ 1);
    compute(t, cur);
    BAR_DRAIN();          // drains in-flight stage AFTER compute (r8 order)
    cur ^= 1;
  }

  const float inv = 1.f / l_acc[0];
  const int qrow = s * 64 + rloc;
#pragma unroll
  for (int ni = 0; ni < 4; ++ni) {
    union { unsigned u[2]; ushort4 s4; } o;
    o.u[0] = cvtpk(oacc[ni][0] * inv, oacc[ni][1] * inv);
    o.u[1] = cvtpk(oacc[ni][2] * inv, oacc[ni][3] * inv);
    *(ushort4*)&O[base + (size_t)qrow * DM + ni * 16 + g * 4] = o.s4;
  }
}

// ---------------- launch ----------------
extern "C" void kernel_launch(void* const* d_in, const int* in_sizes, int n_in,
                              void* d_out, int out_size, void* d_ws, size_t ws_size,
                              hipStream_t stream) {
  const float* x  = (const float*)d_in[0];
  const float* Wq = (const float*)d_in[1];
  const float* Wk = (const float*)d_in[2];
  const float* Wv = (const float*)d_in[3];
  const float* Wo = (const float*)d_in[4];
  const int* pos  = (const int*)d_in[5];
  float* out = (float*)d_out;

  char* ws = (char*)d_ws;
  size_t off = 0;
  auto carve = [&](size_t bytes) -> void* {
    void* p = ws + off;
    off += (bytes + 255) & ~(size_t)255;
    return p;
  };
  unsigned short* xb  = (unsigned short*)carve((size_t)NTOK * DM * 2);
  unsigned short* wqb = (unsigned short*)carve((size_t)DM * DM * 2 * 4);  // Wq|Wk|Wv|Wo contiguous
  unsigned short* wob = wqb + (size_t)3 * DM * DM;
  unsigned short* Qb  = (unsigned short*)carve((size_t)NTOK * DM * 2);
  unsigned short* Kb  = (unsigned short*)carve((size_t)NTOK * DM * 2);
  unsigned short* Ab  = (unsigned short*)carve((size_t)NTOK * DM * 2);
  unsigned short* VTb = (unsigned short*)carve((size_t)4 * NH * DKH * SLEN * 2);

  cast_all_kernel<<<dim3(3072 + 4 * 288), dim3(256), 0, stream>>>(
      x, Wq, Wk, Wv, Wo, xb, wqb);

  gemm_qkv_kernel<<<dim3(18, 128), dim3(256), 0, stream>>>(
      xb, wqb, Qb, Kb, VTb, pos);

  attn_kernel<<<dim3(48, 32), dim3(256), 0, stream>>>(Qb, Kb, VTb, Ab);

  gemm_out_kernel<<<dim3(6, 128), dim3(256), 0, stream>>>(Ab, wob, out);
}

// Round 22
// 116.752 us; speedup vs baseline: 1.0779x; 1.0779x over previous
//
#include <hip/hip_runtime.h>
#include <cstdint>
#include <cstddef>

#define NTOK 8192      // B*S
#define SLEN 2048
#define DM   768
#define NH   12
#define DKH  64

typedef __attribute__((ext_vector_type(8))) short bf16x8;
typedef __attribute__((ext_vector_type(4))) float f32x4;

__device__ __forceinline__ float b2f(unsigned short u) {
  return __uint_as_float(((unsigned)u) << 16);
}
__device__ __forceinline__ unsigned short f2b(float f) {
  unsigned u = __float_as_uint(f);
  u += 0x7fffu + ((u >> 16) & 1u);   // RNE (no NaN inputs here)
  return (unsigned short)(u >> 16);
}
__device__ __forceinline__ unsigned cvtpk(float lo, float hi) {
  unsigned r;
  asm("v_cvt_pk_bf16_f32 %0, %1, %2" : "=v"(r) : "v"(lo), "v"(hi));
  return r;
}

__device__ __forceinline__ void gld16(const void* g, void* l) {
  __builtin_amdgcn_global_load_lds(
      (const __attribute__((address_space(1))) void*)g,
      (__attribute__((address_space(3))) void*)l, 16, 0, 0);
}

#define BAR_DRAIN() do {                                  \
    asm volatile("s_waitcnt vmcnt(0)" ::: "memory");      \
    __builtin_amdgcn_s_barrier();                         \
    __builtin_amdgcn_sched_barrier(0);                    \
  } while (0)

// ---------------- fp32 -> bf16 cast: x + 4 weights in ONE launch -------------
__global__ void cast_all_kernel(const float* __restrict__ x,
                                const float* __restrict__ w0,
                                const float* __restrict__ w1,
                                const float* __restrict__ w2,
                                const float* __restrict__ w3,
                                unsigned short* __restrict__ xb,
                                unsigned short* __restrict__ wb) {
  const int bid = blockIdx.x, tid = threadIdx.x;
  const float* src;
  unsigned short* dst;
  size_t i;
  if (bid < 3072) {
    src = x; dst = xb; i = (size_t)bid * 256 + tid;
  } else {
    const int wbid = bid - 3072;
    const int w = wbid / 288;
    src = (w == 0) ? w0 : (w == 1) ? w1 : (w == 2) ? w2 : w3;
    dst = wb + (size_t)w * DM * DM;
    i = (size_t)(wbid - w * 288) * 256 + tid;
  }
  const float4* p = (const float4*)(src + i * 8);
  float4 a = p[0], b = p[1];
  union { unsigned short h[8]; bf16x8 v; } u;
  u.h[0] = f2b(a.x); u.h[1] = f2b(a.y); u.h[2] = f2b(a.z); u.h[3] = f2b(a.w);
  u.h[4] = f2b(b.x); u.h[5] = f2b(b.y); u.h[6] = f2b(b.z); u.h[7] = f2b(b.w);
  *(bf16x8*)(dst + i * 8) = u.v;
}

// ---------------- unified QKV GEMM: [8192 x 2304] = x @ [Wq;Wk;Wv]^T ---------
// r20-best form (DO NOT dbuf: r21 showed 48KB LDS cuts residency 6->3 blocks
// and loses 20us; cross-block overlap beats explicit pipelining here).
__global__ __launch_bounds__(256, 3) void gemm_qkv_kernel(
    const unsigned short* __restrict__ A, const unsigned short* __restrict__ Ball,
    unsigned short* __restrict__ Qb, unsigned short* __restrict__ Kb,
    unsigned short* __restrict__ VTout,
    const int* __restrict__ pos) {
  const int K = DM;
  const int tid = threadIdx.x, wid = tid >> 6, lane = tid & 63;
  const int lrow = lane & 15, g = lane >> 4, lk8 = g * 8;
  const int m0 = blockIdx.y * 64, n0 = blockIdx.x * 128;
  const int wm = (wid >> 1) * 32, wn = (wid & 1) * 64;
  const int sr = wid * 8 + (lane >> 3), sc = (lane & 7) * 8;
  const int ssw = sc ^ ((sr & 7) << 3);
  __shared__ unsigned short At[64 * 64];
  __shared__ unsigned short Bt[128 * 64];
  f32x4 acc[2][4] = {};

  const unsigned short* ap = A    + (size_t)(m0 + sr) * K + ssw;
  const unsigned short* bp = Ball + (size_t)(n0 + sr) * K + ssw;

  int aoff[2][2], boff[2][4];
#pragma unroll
  for (int ks = 0; ks < 2; ++ks) {
#pragma unroll
    for (int mi = 0; mi < 2; ++mi) {
      int ra = wm + mi * 16 + lrow;
      aoff[ks][mi] = (ra * 64 + ((ks * 32 + lk8) ^ ((ra & 7) << 3))) * 2;
    }
#pragma unroll
    for (int ni = 0; ni < 4; ++ni) {
      int rb = wn + ni * 16 + lrow;
      boff[ks][ni] = (rb * 64 + ((ks * 32 + lk8) ^ ((rb & 7) << 3))) * 2;
    }
  }
  const char* Atc = (const char*)At;
  const char* Btc = (const char*)Bt;

  const int nk = K >> 6;
  for (int kk = 0; kk < nk; ++kk) {
    __syncthreads();
    gld16(ap,          &At[(wid * 8) * 64]);
    gld16(ap + 32 * K, &At[(32 + wid * 8) * 64]);
#pragma unroll
    for (int rnd = 0; rnd < 4; ++rnd)
      gld16(bp + rnd * 32 * K, &Bt[(rnd * 32 + wid * 8) * 64]);
    ap += 64; bp += 64;
    __syncthreads();
    bf16x8 af[2][2], bfr[2][4];
#pragma unroll
    for (int ks = 0; ks < 2; ++ks) {
#pragma unroll
      for (int mi = 0; mi < 2; ++mi)
        af[ks][mi] = *(const bf16x8*)(Atc + aoff[ks][mi]);
#pragma unroll
      for (int ni = 0; ni < 4; ++ni)
        bfr[ks][ni] = *(const bf16x8*)(Btc + boff[ks][ni]);
    }
#pragma unroll
    for (int ks = 0; ks < 2; ++ks)
#pragma unroll
      for (int mi = 0; mi < 2; ++mi)
#pragma unroll
        for (int ni = 0; ni < 4; ++ni)
          acc[mi][ni] = __builtin_amdgcn_mfma_f32_16x16x32_bf16(
              bfr[ks][ni], af[ks][mi], acc[mi][ni], 0, 0, 0);
  }

  const int nsec = blockIdx.x / 6;           // 0=Q, 1=K, 2=V
  const int nn0 = n0 - nsec * 768;

  if (nsec == 2) {                           // V -> transposed+permuted VT
#pragma unroll
    for (int mi = 0; mi < 2; ++mi) {
      const int m = m0 + wm + mi * 16 + lrow;
      const int bb = m >> 11, st = m & (SLEN - 1);
      const int scol = (st & ~63) | (st & 35) |
                       (((st >> 4) & 1) << 2) | (((st >> 2) & 1) << 3) |
                       (((st >> 3) & 1) << 4);
#pragma unroll
      for (int ni = 0; ni < 4; ++ni) {
        const int nb = nn0 + wn + ni * 16 + g * 4;
        const int hh = nb >> 6, dd = nb & 63;
        unsigned short* dst =
            VTout + ((size_t)(bb * NH + hh) * DKH + dd) * SLEN + scol;
#pragma unroll
        for (int r = 0; r < 4; ++r)
          dst[(size_t)r * SLEN] = f2b(acc[mi][ni][r]);
      }
    }
    return;
  }

  unsigned short* Cp = (nsec == 0) ? Qb : Kb;
  float frq[4][2];
#pragma unroll
  for (int ni = 0; ni < 4; ++ni)
#pragma unroll
    for (int rp = 0; rp < 2; ++rp)
      frq[ni][rp] = exp2f(
          (float)(((wn + ni * 16 + g * 4 + rp * 2) & 63) >> 1) *
          -0.4152410118609203f);
#pragma unroll
  for (int mi = 0; mi < 2; ++mi) {
    const int m = m0 + wm + mi * 16 + lrow;
    const float ps = (float)pos[m & (SLEN - 1)];
#pragma unroll
    for (int ni = 0; ni < 4; ++ni) {
#pragma unroll
      for (int rp = 0; rp < 2; ++rp) {
        float sn, cs;
        __sincosf(ps * frq[ni][rp], &sn, &cs);
        float x1 = acc[mi][ni][2 * rp], x2 = acc[mi][ni][2 * rp + 1];
        acc[mi][ni][2 * rp]     = fmaf(x1, cs, -x2 * sn);
        acc[mi][ni][2 * rp + 1] = fmaf(x1, sn, x2 * cs);
      }
      union { unsigned u[2]; ushort4 s; } o;
      o.u[0] = cvtpk(acc[mi][ni][0], acc[mi][ni][1]);
      o.u[1] = cvtpk(acc[mi][ni][2], acc[mi][ni][3]);
      *(ushort4*)&Cp[(size_t)m * DM + nn0 + wn + ni * 16 + g * 4] = o.s;
    }
  }
}

// ---------------- output projection GEMM (plain, fp32 out) -------------------
__global__ __launch_bounds__(256, 3) void gemm_out_kernel(
    const unsigned short* __restrict__ A, const unsigned short* __restrict__ B,
    float* __restrict__ C) {
  const int K = DM, N = DM;
  const int tid = threadIdx.x, wid = tid >> 6, lane = tid & 63;
  const int lrow = lane & 15, g = lane >> 4, lk8 = g * 8;
  const int m0 = blockIdx.y * 64, n0 = blockIdx.x * 128;
  const int wm = (wid >> 1) * 32, wn = (wid & 1) * 64;
  const int sr = wid * 8 + (lane >> 3), sc = (lane & 7) * 8;
  const int ssw = sc ^ ((sr & 7) << 3);
  __shared__ unsigned short At[64 * 64];
  __shared__ unsigned short Bt[128 * 64];
  f32x4 acc[2][4] = {};

  const unsigned short* ap = A + (size_t)(m0 + sr) * K + ssw;
  const unsigned short* bp = B + (size_t)(n0 + sr) * K + ssw;

  int aoff[2][2], boff[2][4];
#pragma unroll
  for (int ks = 0; ks < 2; ++ks) {
#pragma unroll
    for (int mi = 0; mi < 2; ++mi) {
      int ra = wm + mi * 16 + lrow;
      aoff[ks][mi] = (ra * 64 + ((ks * 32 + lk8) ^ ((ra & 7) << 3))) * 2;
    }
#pragma unroll
    for (int ni = 0; ni < 4; ++ni) {
      int rb = wn + ni * 16 + lrow;
      boff[ks][ni] = (rb * 64 + ((ks * 32 + lk8) ^ ((rb & 7) << 3))) * 2;
    }
  }
  const char* Atc = (const char*)At;
  const char* Btc = (const char*)Bt;

  const int nk = K >> 6;
  for (int kk = 0; kk < nk; ++kk) {
    __syncthreads();
    gld16(ap,          &At[(wid * 8) * 64]);
    gld16(ap + 32 * K, &At[(32 + wid * 8) * 64]);
#pragma unroll
    for (int rnd = 0; rnd < 4; ++rnd)
      gld16(bp + rnd * 32 * K, &Bt[(rnd * 32 + wid * 8) * 64]);
    ap += 64; bp += 64;
    __syncthreads();
    bf16x8 af[2][2], bfr[2][4];
#pragma unroll
    for (int ks = 0; ks < 2; ++ks) {
#pragma unroll
      for (int mi = 0; mi < 2; ++mi)
        af[ks][mi] = *(const bf16x8*)(Atc + aoff[ks][mi]);
#pragma unroll
      for (int ni = 0; ni < 4; ++ni)
        bfr[ks][ni] = *(const bf16x8*)(Btc + boff[ks][ni]);
    }
#pragma unroll
    for (int ks = 0; ks < 2; ++ks)
#pragma unroll
      for (int mi = 0; mi < 2; ++mi)
#pragma unroll
        for (int ni = 0; ni < 4; ++ni)
          acc[mi][ni] = __builtin_amdgcn_mfma_f32_16x16x32_bf16(
              bfr[ks][ni], af[ks][mi], acc[mi][ni], 0, 0, 0);
  }

#pragma unroll
  for (int mi = 0; mi < 2; ++mi) {
    const int m = m0 + wm + mi * 16 + lrow;
#pragma unroll
    for (int ni = 0; ni < 4; ++ni)
      *(f32x4*)&C[(size_t)m * N + n0 + wn + ni * 16 + g * 4] = acc[mi][ni];
  }
}

// ---------------- causal flash attention: QBLK=64, best-measured config ------
// (r17/r20 best, byte-identical.)
__global__ __launch_bounds__(256, 4) void attn_kernel(
    const unsigned short* __restrict__ Q, const unsigned short* __restrict__ Kg,
    const unsigned short* __restrict__ VT, unsigned short* __restrict__ O) {
  const int bh = blockIdx.x;                 // %8 pins XCD
  const int s = 31 - (int)blockIdx.y;        // 64-row q-subtile, heavy first
  const int nt = s + 1;                      // kv tiles needed
  const int b = bh / NH, h = bh - b * NH;
  const size_t base = ((size_t)b * SLEN) * DM + h * DKH;
  const size_t vbase = (size_t)bh * DKH * SLEN;
  const int tid = threadIdx.x, wid = tid >> 6, lane = tid & 63;
  const int lrow = lane & 15, g = lane >> 4;
  const int rloc = wid * 16 + lrow;          // row within the 64-row subtile

  __shared__ unsigned short Kt[2][64 * 64];  // 16KB
  __shared__ unsigned short Vt[2][64 * 64];  // 16KB

  bf16x8 qf[2];
#pragma unroll
  for (int ks = 0; ks < 2; ++ks) {
    union { unsigned short h[8]; bf16x8 v; } u;
    u.v = *(const bf16x8*)&Q[base + (size_t)(s * 64 + rloc) * DM + ks * 32 + g * 8];
#pragma unroll
    for (int j = 0; j < 8; ++j)
      u.h[j] = f2b(b2f(u.h[j]) * 0.18033688011112042f);
    qf[ks] = u.v;
  }

  union { unsigned short h[8]; bf16x8 v; } one_u;
#pragma unroll
  for (int j = 0; j < 8; ++j) one_u.h[j] = 0x3F80;
  const bf16x8 ones = one_u.v;

  f32x4 oacc[4] = {};
  f32x4 l_acc = {};

  const int srow = wid * 8 + (lane >> 3);
  const int ssw = ((lane & 7) * 8) ^ ((srow & 7) << 3);
  const unsigned short* kp = Kg + base + (size_t)srow * DM + ssw;
  const unsigned short* vp = VT + vbase + (size_t)srow * SLEN + ssw;

  int roff[2][4];
#pragma unroll
  for (int ks = 0; ks < 2; ++ks)
#pragma unroll
    for (int ni = 0; ni < 4; ++ni) {
      int rr = ni * 16 + lrow;
      roff[ks][ni] = (rr * 64 + ((ks * 32 + g * 8) ^ ((rr & 7) << 3))) * 2;
    }

  auto stage = [&](int buf) {
    gld16(kp,             &Kt[buf][(wid * 8) * 64]);
    gld16(kp + 32 * DM,   &Kt[buf][(32 + wid * 8) * 64]);
    gld16(vp,             &Vt[buf][(wid * 8) * 64]);
    gld16(vp + 32 * SLEN, &Vt[buf][(32 + wid * 8) * 64]);
    kp += 64 * DM;
    vp += 64;
  };

  auto compute = [&](int t, int buf) {
    const char* Ksb = (const char*)&Kt[buf][0];
    const char* Vsb = (const char*)&Vt[buf][0];

    f32x4 sa[4] = {};
    __builtin_amdgcn_s_setprio(1);
#pragma unroll
    for (int ks = 0; ks < 2; ++ks)
#pragma unroll
      for (int ni = 0; ni < 4; ++ni) {
        bf16x8 kf = *(const bf16x8*)(Ksb + roff[ks][ni]);
        sa[ni] = __builtin_amdgcn_mfma_f32_16x16x32_bf16(
            kf, qf[ks], sa[ni], 0, 0, 0);
      }
    __builtin_amdgcn_s_setprio(0);

    if (t == s) {                            // diagonal tile: causal mask
#pragma unroll
      for (int ni = 0; ni < 4; ++ni)
#pragma unroll
        for (int r = 0; r < 4; ++r)
          if (ni * 16 + g * 4 + r > rloc) sa[ni][r] = -1e30f;
    }

#pragma unroll
    for (int ni = 0; ni < 4; ++ni)
#pragma unroll
      for (int r = 0; r < 4; ++r)
        sa[ni][r] = exp2f(sa[ni][r]);

    bf16x8 pf[2];
#pragma unroll
    for (int ks = 0; ks < 2; ++ks) {
      union { unsigned u[4]; bf16x8 v; } uu;
      uu.u[0] = cvtpk(sa[2 * ks][0],     sa[2 * ks][1]);
      uu.u[1] = cvtpk(sa[2 * ks][2],     sa[2 * ks][3]);
      uu.u[2] = cvtpk(sa[2 * ks + 1][0], sa[2 * ks + 1][1]);
      uu.u[3] = cvtpk(sa[2 * ks + 1][2], sa[2 * ks + 1][3]);
      pf[ks] = uu.v;
    }

    __builtin_amdgcn_s_setprio(1);
#pragma unroll
    for (int ks = 0; ks < 2; ++ks) {
#pragma unroll
      for (int ni = 0; ni < 4; ++ni) {
        bf16x8 vf = *(const bf16x8*)(Vsb + roff[ks][ni]);
        oacc[ni] = __builtin_amdgcn_mfma_f32_16x16x32_bf16(
            vf, pf[ks], oacc[ni], 0, 0, 0);
      }
      l_acc = __builtin_amdgcn_mfma_f32_16x16x32_bf16(
          ones, pf[ks], l_acc, 0, 0, 0);
    }
    __builtin_amdgcn_s_setprio(0);
  };

  stage(0);
  BAR_DRAIN();
  int cur = 0;
  for (int t = 0; t < nt; ++t) {
    if (t + 1 < nt) stage(cur ^ 1);
    compute(t, cur);
    BAR_DRAIN();          // drains in-flight stage AFTER compute (r8 order)
    cur ^= 1;
  }

  const float inv = 1.f / l_acc[0];
  const int qrow = s * 64 + rloc;
#pragma unroll
  for (int ni = 0; ni < 4; ++ni) {
    union { unsigned u[2]; ushort4 s4; } o;
    o.u[0] = cvtpk(oacc[ni][0] * inv, oacc[ni][1] * inv);
    o.u[1] = cvtpk(oacc[ni][2] * inv, oacc[ni][3] * inv);
    *(ushort4*)&O[base + (size_t)qrow * DM + ni * 16 + g * 4] = o.s4;
  }
}

// ---------------- launch ----------------
extern "C" void kernel_launch(void* const* d_in, const int* in_sizes, int n_in,
                              void* d_out, int out_size, void* d_ws, size_t ws_size,
                              hipStream_t stream) {
  const float* x  = (const float*)d_in[0];
  const float* Wq = (const float*)d_in[1];
  const float* Wk = (const float*)d_in[2];
  const float* Wv = (const float*)d_in[3];
  const float* Wo = (const float*)d_in[4];
  const int* pos  = (const int*)d_in[5];
  float* out = (float*)d_out;

  char* ws = (char*)d_ws;
  size_t off = 0;
  auto carve = [&](size_t bytes) -> void* {
    void* p = ws + off;
    off += (bytes + 255) & ~(size_t)255;
    return p;
  };
  unsigned short* xb  = (unsigned short*)carve((size_t)NTOK * DM * 2);
  unsigned short* wqb = (unsigned short*)carve((size_t)DM * DM * 2 * 4);  // Wq|Wk|Wv|Wo contiguous
  unsigned short* wob = wqb + (size_t)3 * DM * DM;
  unsigned short* Qb  = (unsigned short*)carve((size_t)NTOK * DM * 2);
  unsigned short* Kb  = (unsigned short*)carve((size_t)NTOK * DM * 2);
  unsigned short* Ab  = (unsigned short*)carve((size_t)NTOK * DM * 2);
  unsigned short* VTb = (unsigned short*)carve((size_t)4 * NH * DKH * SLEN * 2);

  cast_all_kernel<<<dim3(3072 + 4 * 288), dim3(256), 0, stream>>>(
      x, Wq, Wk, Wv, Wo, xb, wqb);

  gemm_qkv_kernel<<<dim3(18, 128), dim3(256), 0, stream>>>(
      xb, wqb, Qb, Kb, VTb, pos);

  attn_kernel<<<dim3(48, 32), dim3(256), 0, stream>>>(Qb, Kb, VTb, Ab);

  gemm_out_kernel<<<dim3(6, 128), dim3(256), 0, stream>>>(Ab, wob, out);
}